// Round 3
// baseline (103.836 us; speedup 1.0000x reference)
//
#include <hip/hip_runtime.h>
#include <hip/hip_bf16.h>

#define NNODES 100000
#define NHE 20000
#define NEDGES 600000

typedef float f32x4 __attribute__((ext_vector_type(4)));
typedef short bf16x8 __attribute__((ext_vector_type(8)));

__device__ __forceinline__ unsigned short f2bf(float f) {
    unsigned u = __builtin_bit_cast(unsigned, f);
    u += 0x7fffu + ((u >> 16) & 1u);
    return (unsigned short)(u >> 16);
}

__device__ __forceinline__ bf16x8 cvt8(f32x4 a, f32x4 b) {
    bf16x8 r;
    r[0] = (short)f2bf(a[0]); r[1] = (short)f2bf(a[1]);
    r[2] = (short)f2bf(a[2]); r[3] = (short)f2bf(a[3]);
    r[4] = (short)f2bf(b[0]); r[5] = (short)f2bf(b[1]);
    r[6] = (short)f2bf(b[2]); r[7] = (short)f2bf(b[3]);
    return r;
}

// Fused: scatter-max over edges (blocks 0..2343) + build wt = W_f^T bf16 [c][k]
// (blocks 2344..2471). last[] is pre-initialized to -1 via hipMemsetAsync(0xFF).
__global__ void k_scatter(const int* __restrict__ sl, int* __restrict__ last,
                          const float* __restrict__ Wf, unsigned short* __restrict__ wt) {
    int b = blockIdx.x, t = threadIdx.x;
    if (b < 2344) {
        int e = b * 256 + t;
        if (e < NEDGES) atomicMax(&last[sl[3 * e]], e);
    } else {
        int idx = (b - 2344) * 256 + t;   // 0..32767
        int k = idx >> 7, c = idx & 127;
        wt[c * 256 + k] = f2bf(Wf[idx]);
    }
}

// out[100000][128] = valid ? [h_emb | node_emb] @ W_f : 0
// Block = 4 independent waves; wave owns a 16x128 tile via 1x8 fragments of
// mfma_f32_16x16x32_bf16. A fragments loaded straight from global in MFMA
// lane layout (row = lane&15, k-slice = lane>>4); B from the wt image
// (L1/L2-resident). No LDS staging, no barriers in the hot path.
__global__ __launch_bounds__(256) void k_main(
    const float* __restrict__ node_emb,
    const float* __restrict__ he_emb,
    const int* __restrict__ sl,
    const int* __restrict__ last,
    const unsigned short* __restrict__ wt,
    float* __restrict__ out)
{
    __shared__ int he_s[64];
    __shared__ int valid_s[64];

    int t = threadIdx.x;
    int r0 = blockIdx.x * 64;

    if (t < 64) {
        int ri = r0 + t;
        int e = (ri < NNODES) ? last[ri] : -1;
        valid_s[t] = (e >= 0) ? 1 : 0;
        he_s[t] = (e >= 0) ? sl[3 * e + 2] : 0;
    }
    __syncthreads();

    int lane = t & 63, w = t >> 6;
    int l15 = lane & 15, l4 = lane >> 4;
    int rw = r0 + w * 16;                       // wave's row base

    int hr = he_s[w * 16 + l15];
    int nr = rw + l15; if (nr >= NNODES) nr = NNODES - 1;
    const float* hp = he_emb + (long)hr * 128 + l4 * 8;     // he rows, k-cols 0..127
    const float* np = node_emb + (long)nr * 128 + l4 * 8;   // node rows
    const unsigned short* wp = wt + (long)l15 * 256 + l4 * 8;

    f32x4 acc[8] = {};
    f32x4 A[2][4];   // [buf][ks*2 + q] : 8 floats per (kc,ks)

    // prefetch kc=0 (he chunk 0)
    A[0][0] = *(const f32x4*)(hp + 0);
    A[0][1] = *(const f32x4*)(hp + 4);
    A[0][2] = *(const f32x4*)(hp + 32);
    A[0][3] = *(const f32x4*)(hp + 36);

    #pragma unroll
    for (int kc = 0; kc < 4; ++kc) {
        // prefetch kc+1 while computing kc
        if (kc < 3) {
            const float* s = (kc + 1 < 2) ? (hp + (kc + 1) * 64) : (np + (kc - 1) * 64);
            A[(kc + 1) & 1][0] = *(const f32x4*)(s + 0);
            A[(kc + 1) & 1][1] = *(const f32x4*)(s + 4);
            A[(kc + 1) & 1][2] = *(const f32x4*)(s + 32);
            A[(kc + 1) & 1][3] = *(const f32x4*)(s + 36);
        }
        #pragma unroll
        for (int ks = 0; ks < 2; ++ks) {
            bf16x8 a = cvt8(A[kc & 1][ks * 2], A[kc & 1][ks * 2 + 1]);
            bf16x8 bw[8];
            #pragma unroll
            for (int fn = 0; fn < 8; ++fn)
                bw[fn] = *(const bf16x8*)(wp + fn * 4096 + kc * 64 + ks * 32);
            #pragma unroll
            for (int fn = 0; fn < 8; ++fn)
                acc[fn] = __builtin_amdgcn_mfma_f32_16x16x32_bf16(a, bw[fn], acc[fn], 0, 0, 0);
        }
    }

    // epilogue: D lane map col = lane&15 (+fn*16), row = (lane>>4)*4 + j
    #pragma unroll
    for (int j = 0; j < 4; ++j) {
        int row = l4 * 4 + j;
        int ri = rw + row;
        if (ri < NNODES) {
            int v = valid_s[w * 16 + row];
            #pragma unroll
            for (int fn = 0; fn < 8; ++fn)
                out[(long)ri * 128 + fn * 16 + l15] = v ? acc[fn][j] : 0.0f;
        }
    }
}

extern "C" void kernel_launch(void* const* d_in, const int* in_sizes, int n_in,
                              void* d_out, int out_size, void* d_ws, size_t ws_size,
                              hipStream_t stream) {
    const float* node_emb = (const float*)d_in[0];
    // d_in[1] = semalink_embeddings : dead (softmax over size-1 axis -> gamma == 1)
    const float* he_emb = (const float*)d_in[2];
    const int* sl = (const int*)d_in[3];
    // d_in[4] = W_a : dead
    const float* Wf = (const float*)d_in[5];
    float* out = (float*)d_out;

    int* last = (int*)d_ws;                                        // 400000 B
    unsigned short* wt = (unsigned short*)((char*)d_ws + 400128);  // 64 KB, aligned

    hipMemsetAsync(last, 0xFF, NNODES * sizeof(int), stream);      // last[i] = -1
    k_scatter<<<2344 + 128, 256, 0, stream>>>(sl, last, Wf, wt);
    k_main<<<(NNODES + 63) / 64, 256, 0, stream>>>(node_emb, he_emb, sl, last, wt, out);
}

// Round 4
// 90.150 us; speedup vs baseline: 1.1518x; 1.1518x over previous
//
#include <hip/hip_runtime.h>
#include <hip/hip_bf16.h>

#define NNODES 100000
#define NHE 20000
#define NEDGES 600000

typedef float f32x4 __attribute__((ext_vector_type(4)));
typedef short bf16x8 __attribute__((ext_vector_type(8)));
typedef short bf16x4 __attribute__((ext_vector_type(4)));

__device__ __forceinline__ unsigned short f2bf(float f) {
    unsigned u = __builtin_bit_cast(unsigned, f);
    u += 0x7fffu + ((u >> 16) & 1u);
    return (unsigned short)(u >> 16);
}
__device__ __forceinline__ float bf2f(unsigned short h) {
    unsigned u = ((unsigned)h) << 16;
    return __builtin_bit_cast(float, u);
}

// Fused: scatter-max (blocks 0..2343) + wt = W_f^T bf16 [c][k<256] (blocks 2344..2471).
// last[] pre-set to -1 by hipMemsetAsync(0xFF).
__global__ void k_sc(const int* __restrict__ sl, int* __restrict__ last,
                     const float* __restrict__ Wf, unsigned short* __restrict__ wt) {
    int b = blockIdx.x, t = threadIdx.x;
    if (b < 2344) {
        int e = b * 256 + t;
        if (e < NEDGES) atomicMax(&last[sl[3 * e]], e);
    } else {
        int idx = (b - 2344) * 256 + t;   // 0..32767
        int k = idx >> 7, c = idx & 127;
        wt[c * 256 + k] = f2bf(Wf[idx]);
    }
}

// heo[20000][128] (bf16) = he_emb @ Wf[0:128]  — streaming MFMA GEMM, BM=64, K=128.
__global__ __launch_bounds__(256) void k_he(
    const float* __restrict__ he_emb,
    const unsigned short* __restrict__ wt,
    unsigned short* __restrict__ heo)
{
    __shared__ __align__(16) unsigned short Xs[64 * 128];  // 16KB swizzled [row][k]
    int t = threadIdx.x;
    int r0 = blockIdx.x * 64;

    #pragma unroll
    for (int i = 0; i < 8; ++i) {
        int idx = i * 256 + t;            // 0..2047 f32x4 slots, 32 per row
        int row = idx >> 5, q = idx & 31;
        int ri = r0 + row; if (ri >= NHE) ri = NHE - 1;
        f32x4 v = *(const f32x4*)(he_emb + (long)ri * 128 + q * 4);
        bf16x4 p;
        p[0] = (short)f2bf(v[0]); p[1] = (short)f2bf(v[1]);
        p[2] = (short)f2bf(v[2]); p[3] = (short)f2bf(v[3]);
        int byte = (row * 256 + q * 8) ^ ((row & 7) << 4);
        *(bf16x4*)((char*)Xs + byte) = p;
    }
    __syncthreads();

    int lane = t & 63, w = t >> 6;
    int wm = w >> 1, wn = w & 1;
    int l15 = lane & 15, l4 = lane >> 4;

    f32x4 acc[2][4] = {};
    #pragma unroll
    for (int kc = 0; kc < 2; ++kc)
        #pragma unroll
        for (int ks = 0; ks < 2; ++ks) {
            bf16x8 a[2], b[4];
            #pragma unroll
            for (int fm = 0; fm < 2; ++fm) {
                int row = wm * 32 + fm * 16 + l15;
                int byte = (row * 256 + kc * 128 + ks * 64 + l4 * 16) ^ ((row & 7) << 4);
                a[fm] = *(const bf16x8*)((const char*)Xs + byte);
            }
            #pragma unroll
            for (int fn = 0; fn < 4; ++fn) {
                int col = wn * 64 + fn * 16 + l15;
                b[fn] = *(const bf16x8*)(wt + (long)col * 256 + kc * 64 + ks * 32 + l4 * 8);
            }
            #pragma unroll
            for (int fm = 0; fm < 2; ++fm)
                #pragma unroll
                for (int fn = 0; fn < 4; ++fn)
                    acc[fm][fn] = __builtin_amdgcn_mfma_f32_16x16x32_bf16(
                        a[fm], b[fn], acc[fm][fn], 0, 0, 0);
        }

    #pragma unroll
    for (int fm = 0; fm < 2; ++fm)
        #pragma unroll
        for (int j = 0; j < 4; ++j) {
            int ri = r0 + wm * 32 + fm * 16 + l4 * 4 + j;
            if (ri < NHE) {
                #pragma unroll
                for (int fn = 0; fn < 4; ++fn) {
                    int col = wn * 64 + fn * 16 + l15;
                    heo[(long)ri * 128 + col] = f2bf(acc[fm][fn][j]);
                }
            }
        }
}

// out[100000][128] = valid ? node_emb @ Wf[128:256] + heo[hsel] : 0
// Pure streaming GEMM (K=128) + cached-table epilogue gather. One barrier.
__global__ __launch_bounds__(256) void k_main(
    const float* __restrict__ node_emb,
    const int* __restrict__ sl,
    const int* __restrict__ last,
    const unsigned short* __restrict__ wt,
    const unsigned short* __restrict__ heo,
    float* __restrict__ out)
{
    __shared__ __align__(16) unsigned short Xs[64 * 128];  // 16KB swizzled
    __shared__ int he_s[64];
    __shared__ int valid_s[64];

    int t = threadIdx.x;
    int r0 = blockIdx.x * 64;

    if (t < 64) {
        int ri = r0 + t;
        int e = (ri < NNODES) ? last[ri] : -1;
        valid_s[t] = (e >= 0) ? 1 : 0;
        he_s[t] = (e >= 0) ? sl[3 * e + 2] : 0;
    }

    #pragma unroll
    for (int i = 0; i < 8; ++i) {
        int idx = i * 256 + t;
        int row = idx >> 5, q = idx & 31;
        int ri = r0 + row; if (ri >= NNODES) ri = NNODES - 1;
        f32x4 v = *(const f32x4*)(node_emb + (long)ri * 128 + q * 4);
        bf16x4 p;
        p[0] = (short)f2bf(v[0]); p[1] = (short)f2bf(v[1]);
        p[2] = (short)f2bf(v[2]); p[3] = (short)f2bf(v[3]);
        int byte = (row * 256 + q * 8) ^ ((row & 7) << 4);
        *(bf16x4*)((char*)Xs + byte) = p;
    }
    __syncthreads();

    int lane = t & 63, w = t >> 6;
    int wm = w >> 1, wn = w & 1;
    int l15 = lane & 15, l4 = lane >> 4;

    f32x4 acc[2][4] = {};
    #pragma unroll
    for (int kc = 0; kc < 2; ++kc)
        #pragma unroll
        for (int ks = 0; ks < 2; ++ks) {
            bf16x8 a[2], b[4];
            #pragma unroll
            for (int fm = 0; fm < 2; ++fm) {
                int row = wm * 32 + fm * 16 + l15;
                int byte = (row * 256 + kc * 128 + ks * 64 + l4 * 16) ^ ((row & 7) << 4);
                a[fm] = *(const bf16x8*)((const char*)Xs + byte);
            }
            #pragma unroll
            for (int fn = 0; fn < 4; ++fn) {
                int col = wn * 64 + fn * 16 + l15;
                b[fn] = *(const bf16x8*)(wt + (long)col * 256 + 128 + kc * 64 + ks * 32 + l4 * 8);
            }
            #pragma unroll
            for (int fm = 0; fm < 2; ++fm)
                #pragma unroll
                for (int fn = 0; fn < 4; ++fn)
                    acc[fm][fn] = __builtin_amdgcn_mfma_f32_16x16x32_bf16(
                        a[fm], b[fn], acc[fm][fn], 0, 0, 0);
        }

    // epilogue: gather he_out row (bf16, L2/L3-hot), add, mask, store
    #pragma unroll
    for (int fm = 0; fm < 2; ++fm)
        #pragma unroll
        for (int j = 0; j < 4; ++j) {
            int lrow = wm * 32 + fm * 16 + l4 * 4 + j;
            int ri = r0 + lrow;
            if (ri < NNODES) {
                int v = valid_s[lrow];
                int hr = he_s[lrow];
                #pragma unroll
                for (int fn = 0; fn < 4; ++fn) {
                    int col = wn * 64 + fn * 16 + l15;
                    float hv = bf2f(heo[(long)hr * 128 + col]);
                    out[(long)ri * 128 + col] = v ? (acc[fm][fn][j] + hv) : 0.0f;
                }
            }
        }
}

extern "C" void kernel_launch(void* const* d_in, const int* in_sizes, int n_in,
                              void* d_out, int out_size, void* d_ws, size_t ws_size,
                              hipStream_t stream) {
    const float* node_emb = (const float*)d_in[0];
    // d_in[1] = semalink_embeddings : dead (softmax over size-1 axis -> gamma == 1)
    const float* he_emb = (const float*)d_in[2];
    const int* sl = (const int*)d_in[3];
    // d_in[4] = W_a : dead
    const float* Wf = (const float*)d_in[5];
    float* out = (float*)d_out;

    int* last = (int*)d_ws;                                         // 400000 B
    unsigned short* wt = (unsigned short*)((char*)d_ws + 400128);   // 64 KB
    unsigned short* heo = (unsigned short*)((char*)d_ws + 465664);  // 5.12 MB (bf16 20000x128)

    hipMemsetAsync(last, 0xFF, NNODES * sizeof(int), stream);       // last[i] = -1
    k_sc<<<2344 + 128, 256, 0, stream>>>(sl, last, Wf, wt);
    k_he<<<(NHE + 63) / 64, 256, 0, stream>>>(he_emb, wt, heo);
    k_main<<<(NNODES + 63) / 64, 256, 0, stream>>>(node_emb, sl, last, wt, heo, out);
}

// Round 5
// 72.309 us; speedup vs baseline: 1.4360x; 1.2467x over previous
//
#include <hip/hip_runtime.h>
#include <hip/hip_bf16.h>

#define NNODES 100000
#define NHE 20000
#define NEDGES 600000

typedef float f32x4 __attribute__((ext_vector_type(4)));
typedef short bf16x8 __attribute__((ext_vector_type(8)));
typedef short bf16x4 __attribute__((ext_vector_type(4)));
typedef unsigned long long u64;

__device__ __forceinline__ unsigned short f2bf(float f) {
    unsigned u = __builtin_bit_cast(unsigned, f);
    u += 0x7fffu + ((u >> 16) & 1u);
    return (unsigned short)(u >> 16);
}
__device__ __forceinline__ float bf2f(unsigned short h) {
    unsigned u = ((unsigned)h) << 16;
    return __builtin_bit_cast(float, u);
}

// Fused: packed scatter-max (blocks 0..2343) + wt = W_f^T bf16 [c][k<256].
// packed[n] = max over edges e of ((e+1)<<32 | h_idx[e])  — one load gives
// k_main both has_edge and the selected hyperedge. packed[] pre-zeroed.
__global__ void k_sc(const int* __restrict__ sl, u64* __restrict__ packed,
                     const float* __restrict__ Wf, unsigned short* __restrict__ wt) {
    int b = blockIdx.x, t = threadIdx.x;
    if (b < 2344) {
        int e = b * 256 + t;
        if (e < NEDGES) {
            int n = sl[3 * e];
            int h = sl[3 * e + 2];
            u64 pk = ((u64)(e + 1) << 32) | (unsigned)h;
            atomicMax(&packed[n], pk);
        }
    } else {
        int idx = (b - 2344) * 256 + t;   // 0..32767
        int k = idx >> 7, c = idx & 127;
        wt[c * 256 + k] = f2bf(Wf[idx]);
    }
}

// heo[20000][128] (bf16) = he_emb @ Wf[0:128]  — streaming MFMA GEMM, BM=64, K=128.
__global__ __launch_bounds__(256) void k_he(
    const float* __restrict__ he_emb,
    const unsigned short* __restrict__ wt,
    unsigned short* __restrict__ heo)
{
    __shared__ __align__(16) unsigned short Xs[64 * 128];
    int t = threadIdx.x;
    int r0 = blockIdx.x * 64;

    #pragma unroll
    for (int i = 0; i < 8; ++i) {
        int idx = i * 256 + t;
        int row = idx >> 5, q = idx & 31;
        int ri = r0 + row; if (ri >= NHE) ri = NHE - 1;
        f32x4 v = *(const f32x4*)(he_emb + (long)ri * 128 + q * 4);
        bf16x4 p;
        p[0] = (short)f2bf(v[0]); p[1] = (short)f2bf(v[1]);
        p[2] = (short)f2bf(v[2]); p[3] = (short)f2bf(v[3]);
        int byte = (row * 256 + q * 8) ^ ((row & 7) << 4);
        *(bf16x4*)((char*)Xs + byte) = p;
    }
    __syncthreads();

    int lane = t & 63, w = t >> 6;
    int wm = w >> 1, wn = w & 1;
    int l15 = lane & 15, l4 = lane >> 4;

    f32x4 acc[2][4] = {};
    #pragma unroll
    for (int kc = 0; kc < 2; ++kc)
        #pragma unroll
        for (int ks = 0; ks < 2; ++ks) {
            bf16x8 a[2], b[4];
            #pragma unroll
            for (int fm = 0; fm < 2; ++fm) {
                int row = wm * 32 + fm * 16 + l15;
                int byte = (row * 256 + kc * 128 + ks * 64 + l4 * 16) ^ ((row & 7) << 4);
                a[fm] = *(const bf16x8*)((const char*)Xs + byte);
            }
            #pragma unroll
            for (int fn = 0; fn < 4; ++fn) {
                int col = wn * 64 + fn * 16 + l15;
                b[fn] = *(const bf16x8*)(wt + (long)col * 256 + kc * 64 + ks * 32 + l4 * 8);
            }
            #pragma unroll
            for (int fm = 0; fm < 2; ++fm)
                #pragma unroll
                for (int fn = 0; fn < 4; ++fn)
                    acc[fm][fn] = __builtin_amdgcn_mfma_f32_16x16x32_bf16(
                        a[fm], b[fn], acc[fm][fn], 0, 0, 0);
        }

    #pragma unroll
    for (int fm = 0; fm < 2; ++fm)
        #pragma unroll
        for (int j = 0; j < 4; ++j) {
            int ri = r0 + wm * 32 + fm * 16 + l4 * 4 + j;
            if (ri < NHE) {
                #pragma unroll
                for (int fn = 0; fn < 4; ++fn) {
                    int col = wn * 64 + fn * 16 + l15;
                    heo[(long)ri * 128 + col] = f2bf(acc[fm][fn][j]);
                }
            }
        }
}

// out = valid ? node_emb @ Wf[128:256] + heo[h] : 0.
// Per block: 1 coalesced packed load -> async heo-row gather into LDS
// (global_load_lds, overlaps the whole MFMA phase); node tile reg-staged to
// swizzled LDS; lgkm-only barrier before MFMA (gathers stay in flight);
// vmcnt(0) barrier only before the epilogue. Nontemporal stores.
__global__ __launch_bounds__(256) void k_main(
    const float* __restrict__ node_emb,
    const u64* __restrict__ packed,
    const unsigned short* __restrict__ wt,
    const unsigned short* __restrict__ heo,
    float* __restrict__ out)
{
    __shared__ __align__(16) unsigned short Xs[64 * 128];  // 16KB swizzled node tile
    __shared__ __align__(16) unsigned short Hs[64 * 128];  // 16KB gathered heo rows (linear)
    __shared__ int valid_s[64];

    int t = threadIdx.x;
    int r0 = blockIdx.x * 64;
    int lane = t & 63, w = t >> 6;
    int l15 = lane & 15, l4 = lane >> 4;

    // 1) wave-local packed load: lane<16 owns row w*16+l15 (issued first)
    u64 p = 0;
    {
        int ri = r0 + w * 16 + l15;
        if (lane < 16 && ri < NNODES) p = packed[ri];
    }

    // 2) node staging loads (independent, in flight with packed)
    f32x4 nv[8];
    #pragma unroll
    for (int i = 0; i < 8; ++i) {
        int idx = i * 256 + t;
        int row = idx >> 5, q = idx & 31;
        int ri = r0 + row; if (ri >= NNODES) ri = NNODES - 1;
        nv[i] = *(const f32x4*)(node_emb + (long)ri * 128 + q * 4);
    }

    // 3) decode, publish valid, launch async heo gather into Hs
    int he16 = (int)(p & 0xffffffffull);
    int v16 = (p != 0) ? 1 : 0;
    if (lane < 16) valid_s[w * 16 + l15] = v16;
    #pragma unroll
    for (int g = 0; g < 4; ++g) {
        int hrow = __shfl(he16, g * 4 + l4, 64);   // he row for output row w*16+g*4+l4
        const char* gsrc = (const char*)(heo + (long)hrow * 128) + l15 * 16;
        // wave-uniform LDS base; HW adds lane*16
        __builtin_amdgcn_global_load_lds(
            (const __attribute__((address_space(1))) void*)gsrc,
            (__attribute__((address_space(3))) void*)&Hs[(w * 16 + g * 4) * 128],
            16, 0, 0);
    }

    // 4) convert node regs -> swizzled LDS (compiler auto-waits nv)
    #pragma unroll
    for (int i = 0; i < 8; ++i) {
        int idx = i * 256 + t;
        int row = idx >> 5, q = idx & 31;
        bf16x4 pk;
        pk[0] = (short)f2bf(nv[i][0]); pk[1] = (short)f2bf(nv[i][1]);
        pk[2] = (short)f2bf(nv[i][2]); pk[3] = (short)f2bf(nv[i][3]);
        int byte = (row * 256 + q * 8) ^ ((row & 7) << 4);
        *(bf16x4*)((char*)Xs + byte) = pk;
    }

    // 5) barrier draining LDS only — heo gathers stay in flight
    asm volatile("s_waitcnt lgkmcnt(0)" ::: "memory");
    __builtin_amdgcn_sched_barrier(0);
    __builtin_amdgcn_s_barrier();
    __builtin_amdgcn_sched_barrier(0);

    // 6) GEMM: K=128 vs Wf bottom half
    int wm = w >> 1, wn = w & 1;
    f32x4 acc[2][4] = {};
    #pragma unroll
    for (int kc = 0; kc < 2; ++kc)
        #pragma unroll
        for (int ks = 0; ks < 2; ++ks) {
            bf16x8 a[2], b[4];
            #pragma unroll
            for (int fm = 0; fm < 2; ++fm) {
                int row = wm * 32 + fm * 16 + l15;
                int byte = (row * 256 + kc * 128 + ks * 64 + l4 * 16) ^ ((row & 7) << 4);
                a[fm] = *(const bf16x8*)((const char*)Xs + byte);
            }
            #pragma unroll
            for (int fn = 0; fn < 4; ++fn) {
                int col = wn * 64 + fn * 16 + l15;
                b[fn] = *(const bf16x8*)(wt + (long)col * 256 + 128 + kc * 64 + ks * 32 + l4 * 8);
            }
            #pragma unroll
            for (int fm = 0; fm < 2; ++fm)
                #pragma unroll
                for (int fn = 0; fn < 4; ++fn)
                    acc[fm][fn] = __builtin_amdgcn_mfma_f32_16x16x32_bf16(
                        a[fm], b[fn], acc[fm][fn], 0, 0, 0);
        }

    // 7) gathers + all LDS done before cross-wave Hs reads
    asm volatile("s_waitcnt vmcnt(0) lgkmcnt(0)" ::: "memory");
    __builtin_amdgcn_sched_barrier(0);
    __builtin_amdgcn_s_barrier();
    __builtin_amdgcn_sched_barrier(0);

    // 8) epilogue: add gathered he row, mask, nontemporal store
    #pragma unroll
    for (int fm = 0; fm < 2; ++fm)
        #pragma unroll
        for (int j = 0; j < 4; ++j) {
            int lrow = wm * 32 + fm * 16 + l4 * 4 + j;
            int ri = r0 + lrow;
            if (ri < NNODES) {
                int v = valid_s[lrow];
                #pragma unroll
                for (int fn = 0; fn < 4; ++fn) {
                    int col = wn * 64 + fn * 16 + l15;
                    float hv = bf2f(Hs[lrow * 128 + col]);
                    float val = v ? (acc[fm][fn][j] + hv) : 0.0f;
                    __builtin_nontemporal_store(val, &out[(long)ri * 128 + col]);
                }
            }
        }
}

extern "C" void kernel_launch(void* const* d_in, const int* in_sizes, int n_in,
                              void* d_out, int out_size, void* d_ws, size_t ws_size,
                              hipStream_t stream) {
    const float* node_emb = (const float*)d_in[0];
    // d_in[1] = semalink_embeddings : dead (softmax over size-1 axis -> gamma == 1)
    const float* he_emb = (const float*)d_in[2];
    const int* sl = (const int*)d_in[3];
    // d_in[4] = W_a : dead
    const float* Wf = (const float*)d_in[5];
    float* out = (float*)d_out;

    u64* packed = (u64*)d_ws;                                       // 800000 B
    unsigned short* wt = (unsigned short*)((char*)d_ws + 800000);   // 64 KB
    unsigned short* heo = (unsigned short*)((char*)d_ws + 865536);  // 5.12 MB

    hipMemsetAsync(packed, 0, NNODES * sizeof(u64), stream);
    k_sc<<<2344 + 128, 256, 0, stream>>>(sl, packed, Wf, wt);
    k_he<<<(NHE + 63) / 64, 256, 0, stream>>>(he_emb, wt, heo);
    k_main<<<(NNODES + 63) / 64, 256, 0, stream>>>(node_emb, packed, wt, heo, out);
}

// Round 6
// 68.904 us; speedup vs baseline: 1.5070x; 1.0494x over previous
//
#include <hip/hip_runtime.h>
#include <hip/hip_bf16.h>

#define NNODES 100000
#define NHE 20000
#define NEDGES 600000

typedef float f32x4 __attribute__((ext_vector_type(4)));
typedef short bf16x8 __attribute__((ext_vector_type(8)));
typedef short bf16x4 __attribute__((ext_vector_type(4)));
typedef unsigned long long u64;

__device__ __forceinline__ unsigned short f2bf(float f) {
    unsigned u = __builtin_bit_cast(unsigned, f);
    u += 0x7fffu + ((u >> 16) & 1u);
    return (unsigned short)(u >> 16);
}
__device__ __forceinline__ float bf2f(unsigned short h) {
    unsigned u = ((unsigned)h) << 16;
    return __builtin_bit_cast(float, u);
}

// k0: zero packed[] with 16B stores (blocks 0..195) + wt = W_f^T bf16 [c][k]
// (blocks 196..323). Replaces the 40us hipMemsetAsync fill.
__global__ void k0(u64* __restrict__ packed, const float* __restrict__ Wf,
                   unsigned short* __restrict__ wt) {
    int b = blockIdx.x, t = threadIdx.x;
    if (b < 196) {
        int i = b * 256 + t;              // 16B slot index, 50000 slots
        if (i < NNODES / 2) ((f32x4*)packed)[i] = (f32x4){0.f, 0.f, 0.f, 0.f};
    } else {
        int idx = (b - 196) * 256 + t;    // 0..32767
        int k = idx >> 7, c = idx & 127;
        wt[c * 256 + k] = f2bf(Wf[idx]);
    }
}

// k1: fused independent phases —
//  blocks 0..2343: packed[n] = atomicMax((e+1)<<32 | h) over edges
//  blocks 2344..2656: heo[20000][128] bf16 = he_emb @ Wf[0:128] (BM=64, K=128)
__global__ __launch_bounds__(256) void k1(
    const int* __restrict__ sl, u64* __restrict__ packed,
    const float* __restrict__ he_emb, const unsigned short* __restrict__ wt,
    unsigned short* __restrict__ heo)
{
    int b = blockIdx.x, t = threadIdx.x;
    if (b < 2344) {
        int e = b * 256 + t;
        if (e < NEDGES) {
            int n = sl[3 * e];
            int h = sl[3 * e + 2];
            atomicMax(&packed[n], ((u64)(e + 1) << 32) | (unsigned)h);
        }
        return;
    }

    __shared__ __align__(16) unsigned short Xs[64 * 128];
    int r0 = (b - 2344) * 64;

    #pragma unroll
    for (int i = 0; i < 8; ++i) {
        int idx = i * 256 + t;
        int row = idx >> 5, q = idx & 31;
        int ri = r0 + row; if (ri >= NHE) ri = NHE - 1;
        f32x4 v = *(const f32x4*)(he_emb + (long)ri * 128 + q * 4);
        bf16x4 p;
        p[0] = (short)f2bf(v[0]); p[1] = (short)f2bf(v[1]);
        p[2] = (short)f2bf(v[2]); p[3] = (short)f2bf(v[3]);
        int byte = (row * 256 + q * 8) ^ ((row & 7) << 4);
        *(bf16x4*)((char*)Xs + byte) = p;
    }
    __syncthreads();

    int lane = t & 63, w = t >> 6;
    int wm = w >> 1, wn = w & 1;
    int l15 = lane & 15, l4 = lane >> 4;

    f32x4 acc[2][4] = {};
    #pragma unroll
    for (int kc = 0; kc < 2; ++kc)
        #pragma unroll
        for (int ks = 0; ks < 2; ++ks) {
            bf16x8 a[2], bb[4];
            #pragma unroll
            for (int fm = 0; fm < 2; ++fm) {
                int row = wm * 32 + fm * 16 + l15;
                int byte = (row * 256 + kc * 128 + ks * 64 + l4 * 16) ^ ((row & 7) << 4);
                a[fm] = *(const bf16x8*)((const char*)Xs + byte);
            }
            #pragma unroll
            for (int fn = 0; fn < 4; ++fn) {
                int col = wn * 64 + fn * 16 + l15;
                bb[fn] = *(const bf16x8*)(wt + (long)col * 256 + kc * 64 + ks * 32 + l4 * 8);
            }
            #pragma unroll
            for (int fm = 0; fm < 2; ++fm)
                #pragma unroll
                for (int fn = 0; fn < 4; ++fn)
                    acc[fm][fn] = __builtin_amdgcn_mfma_f32_16x16x32_bf16(
                        a[fm], bb[fn], acc[fm][fn], 0, 0, 0);
        }

    #pragma unroll
    for (int fm = 0; fm < 2; ++fm)
        #pragma unroll
        for (int j = 0; j < 4; ++j) {
            int ri = r0 + wm * 32 + fm * 16 + l4 * 4 + j;
            if (ri < NHE) {
                #pragma unroll
                for (int fn = 0; fn < 4; ++fn) {
                    int col = wn * 64 + fn * 16 + l15;
                    heo[(long)ri * 128 + col] = f2bf(acc[fm][fn][j]);
                }
            }
        }
}

// out = valid ? node_emb @ Wf[128:256] + heo[h] : 0.
__global__ __launch_bounds__(256) void k_main(
    const float* __restrict__ node_emb,
    const u64* __restrict__ packed,
    const unsigned short* __restrict__ wt,
    const unsigned short* __restrict__ heo,
    float* __restrict__ out)
{
    __shared__ __align__(16) unsigned short Xs[64 * 128];  // swizzled node tile
    __shared__ __align__(16) unsigned short Hs[64 * 128];  // gathered heo rows (linear)
    __shared__ int valid_s[64];

    int t = threadIdx.x;
    int r0 = blockIdx.x * 64;
    int lane = t & 63, w = t >> 6;
    int l15 = lane & 15, l4 = lane >> 4;

    // 1) wave-local packed load: lane<16 owns row w*16+l15
    u64 p = 0;
    {
        int ri = r0 + w * 16 + l15;
        if (lane < 16 && ri < NNODES) p = packed[ri];
    }

    // 2) node staging loads (independent, in flight with packed)
    f32x4 nv[8];
    #pragma unroll
    for (int i = 0; i < 8; ++i) {
        int idx = i * 256 + t;
        int row = idx >> 5, q = idx & 31;
        int ri = r0 + row; if (ri >= NNODES) ri = NNODES - 1;
        nv[i] = *(const f32x4*)(node_emb + (long)ri * 128 + q * 4);
    }

    // 3) decode, publish valid, launch async heo gather into Hs
    int he16 = (int)(p & 0xffffffffull);
    int v16 = (p != 0) ? 1 : 0;
    if (lane < 16) valid_s[w * 16 + l15] = v16;
    #pragma unroll
    for (int g = 0; g < 4; ++g) {
        int hrow = __shfl(he16, g * 4 + l4, 64);
        const char* gsrc = (const char*)(heo + (long)hrow * 128) + l15 * 16;
        __builtin_amdgcn_global_load_lds(
            (const __attribute__((address_space(1))) void*)gsrc,
            (__attribute__((address_space(3))) void*)&Hs[(w * 16 + g * 4) * 128],
            16, 0, 0);
    }

    // 4) convert node regs -> swizzled LDS
    #pragma unroll
    for (int i = 0; i < 8; ++i) {
        int idx = i * 256 + t;
        int row = idx >> 5, q = idx & 31;
        bf16x4 pk;
        pk[0] = (short)f2bf(nv[i][0]); pk[1] = (short)f2bf(nv[i][1]);
        pk[2] = (short)f2bf(nv[i][2]); pk[3] = (short)f2bf(nv[i][3]);
        int byte = (row * 256 + q * 8) ^ ((row & 7) << 4);
        *(bf16x4*)((char*)Xs + byte) = pk;
    }

    // 5) barrier draining LDS only — heo gathers stay in flight
    asm volatile("s_waitcnt lgkmcnt(0)" ::: "memory");
    __builtin_amdgcn_sched_barrier(0);
    __builtin_amdgcn_s_barrier();
    __builtin_amdgcn_sched_barrier(0);

    // 6) GEMM: K=128 vs Wf bottom half
    int wm = w >> 1, wn = w & 1;
    f32x4 acc[2][4] = {};
    #pragma unroll
    for (int kc = 0; kc < 2; ++kc)
        #pragma unroll
        for (int ks = 0; ks < 2; ++ks) {
            bf16x8 a[2], b[4];
            #pragma unroll
            for (int fm = 0; fm < 2; ++fm) {
                int row = wm * 32 + fm * 16 + l15;
                int byte = (row * 256 + kc * 128 + ks * 64 + l4 * 16) ^ ((row & 7) << 4);
                a[fm] = *(const bf16x8*)((const char*)Xs + byte);
            }
            #pragma unroll
            for (int fn = 0; fn < 4; ++fn) {
                int col = wn * 64 + fn * 16 + l15;
                b[fn] = *(const bf16x8*)(wt + (long)col * 256 + 128 + kc * 64 + ks * 32 + l4 * 8);
            }
            #pragma unroll
            for (int fm = 0; fm < 2; ++fm)
                #pragma unroll
                for (int fn = 0; fn < 4; ++fn)
                    acc[fm][fn] = __builtin_amdgcn_mfma_f32_16x16x32_bf16(
                        a[fm], b[fn], acc[fm][fn], 0, 0, 0);
        }

    // 7) gathers + all LDS done before cross-wave Hs reads
    asm volatile("s_waitcnt vmcnt(0) lgkmcnt(0)" ::: "memory");
    __builtin_amdgcn_sched_barrier(0);
    __builtin_amdgcn_s_barrier();
    __builtin_amdgcn_sched_barrier(0);

    // 8) epilogue: add gathered he row, mask, nontemporal store
    #pragma unroll
    for (int fm = 0; fm < 2; ++fm)
        #pragma unroll
        for (int j = 0; j < 4; ++j) {
            int lrow = wm * 32 + fm * 16 + l4 * 4 + j;
            int ri = r0 + lrow;
            if (ri < NNODES) {
                int v = valid_s[lrow];
                #pragma unroll
                for (int fn = 0; fn < 4; ++fn) {
                    int col = wn * 64 + fn * 16 + l15;
                    float hv = bf2f(Hs[lrow * 128 + col]);
                    float val = v ? (acc[fm][fn][j] + hv) : 0.0f;
                    __builtin_nontemporal_store(val, &out[(long)ri * 128 + col]);
                }
            }
        }
}

extern "C" void kernel_launch(void* const* d_in, const int* in_sizes, int n_in,
                              void* d_out, int out_size, void* d_ws, size_t ws_size,
                              hipStream_t stream) {
    const float* node_emb = (const float*)d_in[0];
    // d_in[1] = semalink_embeddings : dead (softmax over size-1 axis -> gamma == 1)
    const float* he_emb = (const float*)d_in[2];
    const int* sl = (const int*)d_in[3];
    // d_in[4] = W_a : dead
    const float* Wf = (const float*)d_in[5];
    float* out = (float*)d_out;

    u64* packed = (u64*)d_ws;                                       // 800000 B
    unsigned short* wt = (unsigned short*)((char*)d_ws + 800000);   // 64 KB
    unsigned short* heo = (unsigned short*)((char*)d_ws + 865536);  // 5.12 MB

    k0<<<324, 256, 0, stream>>>(packed, Wf, wt);
    k1<<<2344 + 313, 256, 0, stream>>>(sl, packed, he_emb, wt, heo);
    k_main<<<(NNODES + 63) / 64, 256, 0, stream>>>(node_emb, packed, wt, heo, out);
}

// Round 7
// 68.718 us; speedup vs baseline: 1.5110x; 1.0027x over previous
//
#include <hip/hip_runtime.h>
#include <hip/hip_bf16.h>

#define NNODES 100000
#define NHE 20000
#define NEDGES 600000

typedef float f32x4 __attribute__((ext_vector_type(4)));
typedef short bf16x8 __attribute__((ext_vector_type(8)));
typedef short bf16x4 __attribute__((ext_vector_type(4)));
typedef int i32x4 __attribute__((ext_vector_type(4)));
typedef unsigned long long u64;

__device__ __forceinline__ unsigned short f2bf(float f) {
    unsigned u = __builtin_bit_cast(unsigned, f);
    u += 0x7fffu + ((u >> 16) & 1u);
    return (unsigned short)(u >> 16);
}
__device__ __forceinline__ float bf2f(unsigned short h) {
    unsigned u = ((unsigned)h) << 16;
    return __builtin_bit_cast(float, u);
}

// k0: zero packed[] with 16B stores (blocks 0..195) + wt = W_f^T bf16 [c][k]
__global__ void k0(u64* __restrict__ packed, const float* __restrict__ Wf,
                   unsigned short* __restrict__ wt) {
    int b = blockIdx.x, t = threadIdx.x;
    if (b < 196) {
        int i = b * 256 + t;
        if (i < NNODES / 2) ((f32x4*)packed)[i] = (f32x4){0.f, 0.f, 0.f, 0.f};
    } else {
        int idx = (b - 196) * 256 + t;
        int k = idx >> 7, c = idx & 127;
        wt[c * 256 + k] = f2bf(Wf[idx]);
    }
}

// k1: fused — blocks 0..585: vectorized scatter (4 edges/thread, 3x int4);
//             blocks 586..898: heo = he_emb @ Wf[0:128] (BM=64, K=128, swapped mfma)
__global__ __launch_bounds__(256) void k1(
    const int* __restrict__ sl, u64* __restrict__ packed,
    const float* __restrict__ he_emb, const unsigned short* __restrict__ wt,
    unsigned short* __restrict__ heo)
{
    int b = blockIdx.x, t = threadIdx.x;
    if (b < 586) {
        int tg = b * 256 + t;                 // thread handles edges 4tg..4tg+3
        if (tg < NEDGES / 4) {
            const i32x4* s4 = (const i32x4*)sl;
            i32x4 a = s4[3 * tg], bb = s4[3 * tg + 1], c = s4[3 * tg + 2];
            int e0 = 4 * tg;
            atomicMax(&packed[a[0]], ((u64)(e0 + 1) << 32) | (unsigned)a[2]);
            atomicMax(&packed[a[3]], ((u64)(e0 + 2) << 32) | (unsigned)bb[1]);
            atomicMax(&packed[bb[2]], ((u64)(e0 + 3) << 32) | (unsigned)c[0]);
            atomicMax(&packed[c[1]], ((u64)(e0 + 4) << 32) | (unsigned)c[3]);
        }
        return;
    }

    __shared__ __align__(16) unsigned short Xs[64 * 128];
    int r0 = (b - 586) * 64;

    #pragma unroll
    for (int i = 0; i < 8; ++i) {
        int idx = i * 256 + t;
        int row = idx >> 5, q = idx & 31;
        int ri = r0 + row; if (ri >= NHE) ri = NHE - 1;
        f32x4 v = *(const f32x4*)(he_emb + (long)ri * 128 + q * 4);
        bf16x4 p;
        p[0] = (short)f2bf(v[0]); p[1] = (short)f2bf(v[1]);
        p[2] = (short)f2bf(v[2]); p[3] = (short)f2bf(v[3]);
        int byte = (row * 256 + q * 8) ^ ((row & 7) << 4);
        *(bf16x4*)((char*)Xs + byte) = p;
    }
    __syncthreads();

    int lane = t & 63, w = t >> 6;
    int wm = w >> 1, wn = w & 1;
    int l15 = lane & 15, l4 = lane >> 4;

    f32x4 acc[2][4] = {};
    #pragma unroll
    for (int kc = 0; kc < 2; ++kc)
        #pragma unroll
        for (int ks = 0; ks < 2; ++ks) {
            bf16x8 a[2], bb[4];
            #pragma unroll
            for (int fm = 0; fm < 2; ++fm) {
                int row = wm * 32 + fm * 16 + l15;
                int byte = (row * 256 + kc * 128 + ks * 64 + l4 * 16) ^ ((row & 7) << 4);
                a[fm] = *(const bf16x8*)((const char*)Xs + byte);
            }
            #pragma unroll
            for (int fn = 0; fn < 4; ++fn) {
                int col = wn * 64 + fn * 16 + l15;
                bb[fn] = *(const bf16x8*)(wt + (long)col * 256 + kc * 64 + ks * 32 + l4 * 8);
            }
            // swapped operands: D col = node row (l15), D row = out col (l4*4+j)
            #pragma unroll
            for (int fm = 0; fm < 2; ++fm)
                #pragma unroll
                for (int fn = 0; fn < 4; ++fn)
                    acc[fm][fn] = __builtin_amdgcn_mfma_f32_16x16x32_bf16(
                        bb[fn], a[fm], acc[fm][fn], 0, 0, 0);
        }

    // epilogue: lane owns row r0+wm*32+fm*16+l15, cols wn*64+fn*16+l4*4+(0..3)
    #pragma unroll
    for (int fm = 0; fm < 2; ++fm) {
        int ri = r0 + wm * 32 + fm * 16 + l15;
        if (ri < NHE) {
            #pragma unroll
            for (int fn = 0; fn < 4; ++fn) {
                bf16x4 p;
                p[0] = (short)f2bf(acc[fm][fn][0]);
                p[1] = (short)f2bf(acc[fm][fn][1]);
                p[2] = (short)f2bf(acc[fm][fn][2]);
                p[3] = (short)f2bf(acc[fm][fn][3]);
                *(bf16x4*)(heo + (long)ri * 128 + wn * 64 + fn * 16 + l4 * 4) = p;
            }
        }
    }
}

// out = valid ? node_emb @ Wf[128:256] + heo[h] : 0.  Swapped-mfma layout:
// vectorized dwordx4 stores; Hs gather chunk-XOR-swizzled for conflict-free
// ds_read_b64 in the epilogue.
__global__ __launch_bounds__(256) void k_main(
    const float* __restrict__ node_emb,
    const u64* __restrict__ packed,
    const unsigned short* __restrict__ wt,
    const unsigned short* __restrict__ heo,
    float* __restrict__ out)
{
    __shared__ __align__(16) unsigned short Xs[64 * 128];  // swizzled node tile
    __shared__ __align__(16) unsigned short Hs[64 * 128];  // gathered heo rows, chunk-XOR'd
    __shared__ int valid_s[64];

    int t = threadIdx.x;
    int r0 = blockIdx.x * 64;
    int lane = t & 63, w = t >> 6;
    int l15 = lane & 15, l4 = lane >> 4;

    // 1) wave-local packed load: lane<16 owns row w*16+l15
    u64 p = 0;
    {
        int ri = r0 + w * 16 + l15;
        if (lane < 16 && ri < NNODES) p = packed[ri];
    }

    // 2) node staging loads
    f32x4 nv[8];
    #pragma unroll
    for (int i = 0; i < 8; ++i) {
        int idx = i * 256 + t;
        int row = idx >> 5, q = idx & 31;
        int ri = r0 + row; if (ri >= NNODES) ri = NNODES - 1;
        nv[i] = *(const f32x4*)(node_emb + (long)ri * 128 + q * 4);
    }

    // 3) decode, publish valid, async heo gather with chunk-XOR pre-swizzle:
    //    LDS chunk l15 of row r holds global chunk l15 ^ (r&15)
    int he16 = (int)(p & 0xffffffffull);
    int v16 = (p != 0) ? 1 : 0;
    if (lane < 16) valid_s[w * 16 + l15] = v16;
    #pragma unroll
    for (int g = 0; g < 4; ++g) {
        int hrow = __shfl(he16, g * 4 + l4, 64);
        int rlow = (g * 4 + l4) & 15;
        const char* gsrc = (const char*)(heo + (long)hrow * 128) + ((l15 ^ rlow) * 16);
        __builtin_amdgcn_global_load_lds(
            (const __attribute__((address_space(1))) void*)gsrc,
            (__attribute__((address_space(3))) void*)&Hs[(w * 16 + g * 4) * 128],
            16, 0, 0);
    }

    // 4) node regs -> swizzled LDS
    #pragma unroll
    for (int i = 0; i < 8; ++i) {
        int idx = i * 256 + t;
        int row = idx >> 5, q = idx & 31;
        bf16x4 pk;
        pk[0] = (short)f2bf(nv[i][0]); pk[1] = (short)f2bf(nv[i][1]);
        pk[2] = (short)f2bf(nv[i][2]); pk[3] = (short)f2bf(nv[i][3]);
        int byte = (row * 256 + q * 8) ^ ((row & 7) << 4);
        *(bf16x4*)((char*)Xs + byte) = pk;
    }

    // 5) barrier draining LDS only — heo gathers stay in flight
    asm volatile("s_waitcnt lgkmcnt(0)" ::: "memory");
    __builtin_amdgcn_sched_barrier(0);
    __builtin_amdgcn_s_barrier();
    __builtin_amdgcn_sched_barrier(0);

    // 6) GEMM (swapped operands)
    int wm = w >> 1, wn = w & 1;
    f32x4 acc[2][4] = {};
    #pragma unroll
    for (int kc = 0; kc < 2; ++kc)
        #pragma unroll
        for (int ks = 0; ks < 2; ++ks) {
            bf16x8 a[2], b[4];
            #pragma unroll
            for (int fm = 0; fm < 2; ++fm) {
                int row = wm * 32 + fm * 16 + l15;
                int byte = (row * 256 + kc * 128 + ks * 64 + l4 * 16) ^ ((row & 7) << 4);
                a[fm] = *(const bf16x8*)((const char*)Xs + byte);
            }
            #pragma unroll
            for (int fn = 0; fn < 4; ++fn) {
                int col = wn * 64 + fn * 16 + l15;
                b[fn] = *(const bf16x8*)(wt + (long)col * 256 + 128 + kc * 64 + ks * 32 + l4 * 8);
            }
            #pragma unroll
            for (int fm = 0; fm < 2; ++fm)
                #pragma unroll
                for (int fn = 0; fn < 4; ++fn)
                    acc[fm][fn] = __builtin_amdgcn_mfma_f32_16x16x32_bf16(
                        b[fn], a[fm], acc[fm][fn], 0, 0, 0);
        }

    // 7) gathers + LDS done before cross-wave Hs reads
    asm volatile("s_waitcnt vmcnt(0) lgkmcnt(0)" ::: "memory");
    __builtin_amdgcn_sched_barrier(0);
    __builtin_amdgcn_s_barrier();
    __builtin_amdgcn_sched_barrier(0);

    // 8) epilogue: lane owns row r0+wm*32+fm*16+l15, cols wn*64+fn*16+l4*4+(0..3)
    #pragma unroll
    for (int fm = 0; fm < 2; ++fm) {
        int lrow = wm * 32 + fm * 16 + l15;
        int ri = r0 + lrow;
        int v = valid_s[lrow];
        if (ri < NNODES) {
            #pragma unroll
            for (int fn = 0; fn < 4; ++fn) {
                // global chunk index of this 16B-col-group, XOR-unswizzled
                int chunk = wn * 8 + fn * 2 + (l4 >> 1);
                int byte = lrow * 256 + ((chunk ^ l15) * 16) + (l4 & 1) * 8;
                bf16x4 hv = *(const bf16x4*)((const char*)Hs + byte);
                f32x4 o;
                #pragma unroll
                for (int jj = 0; jj < 4; ++jj)
                    o[jj] = v ? (acc[fm][fn][jj] + bf2f((unsigned short)hv[jj])) : 0.0f;
                __builtin_nontemporal_store(o,
                    (f32x4*)(out + (long)ri * 128 + wn * 64 + fn * 16 + l4 * 4));
            }
        }
    }
}

extern "C" void kernel_launch(void* const* d_in, const int* in_sizes, int n_in,
                              void* d_out, int out_size, void* d_ws, size_t ws_size,
                              hipStream_t stream) {
    const float* node_emb = (const float*)d_in[0];
    // d_in[1] = semalink_embeddings : dead (softmax over size-1 axis -> gamma == 1)
    const float* he_emb = (const float*)d_in[2];
    const int* sl = (const int*)d_in[3];
    // d_in[4] = W_a : dead
    const float* Wf = (const float*)d_in[5];
    float* out = (float*)d_out;

    u64* packed = (u64*)d_ws;                                       // 800000 B
    unsigned short* wt = (unsigned short*)((char*)d_ws + 800000);   // 64 KB
    unsigned short* heo = (unsigned short*)((char*)d_ws + 865536);  // 5.12 MB

    k0<<<324, 256, 0, stream>>>(packed, Wf, wt);
    k1<<<586 + 313, 256, 0, stream>>>(sl, packed, he_emb, wt, heo);
    k_main<<<(NNODES + 63) / 64, 256, 0, stream>>>(node_emb, packed, wt, heo, out);
}